// Round 9
// baseline (15.661 us; speedup 1.0000x reference)
//
#include <hip/hip_runtime.h>

// PrRoI pooling (exact bilinear-integral) for feat [64,256,72,72] f32,
// bb [64,4] (x,y,w,h image coords, stride 16), out [64,256,4,4] f32.
//
// Separable weights: out[p][q] = (1/area) * sum_w gx[q][w] * sum_h gy[p][h] * f[h][w].
// Block = 256 threads (4 waves) = one n x 8 channels; grid 2048 (8 blocks/CU).
// n = bid >> 5 so a CU's resident blocks carry different ROI sizes.
//
//   phase 1: each wave does 2 channels; lane = (col 0..31, row-parity 0..1);
//            h-loop unrolled to 15 chunks (row span <= 30). Chunk k's loads
//            are guarded by the BLOCK-UNIFORM condition j0+2k <= j1 (scalar
//            branch, no exec-mask divergence): on average only ~9 of 15
//            chunks issue loads; f[] is pre-zeroed and gy weights past j1
//            are exact zeros, so skipped chunks contribute nothing. Valid
//            loads still issue back-to-back -> one exposed latency round.
//            Columns past i1 clamp to i1, rows past j1 (parity tail) clamp
//            to j1: duplicate reads of already-fetched lines, no extra HBM.
//   phase 2: LDS transpose-reduce: thread t<128 owns output (ch,p,q) = t and
//            dots s_row[64] with gx[q][64] via float4 LDS reads.
//
// NOTE: no __launch_bounds__ min-wave cap — forcing 64 VGPRs spilled the
// inner loop in round 4 (19.3 -> 43.4 us).

constexpr int N_ = 64;
constexpr int C_ = 256;
constexpr int H_ = 72;
constexpr int W_ = 72;
constexpr int HW_ = H_ * W_;
constexpr int CPW = 2;               // channels per wave
constexpr int NW  = 4;               // waves per block
constexpr int CPB = CPW * NW;        // 8 channels per block
constexpr int SPAD = 68;             // padded row length (floats)
constexpr int GYR = 32;              // gy rows incl. zero padding (max r = 29)
constexpr int KCH = 15;              // row chunks per parity (span <= 30)

__device__ __forceinline__ float Gfun(float u) {
    // Antiderivative of max(0, 1-|u|), clipped so G(-1)=0, G(1)=1.
    u = fminf(1.0f, fmaxf(-1.0f, u));
    return (u <= 0.0f) ? (0.5f * (u + 1.0f) * (u + 1.0f))
                       : (1.0f - 0.5f * (1.0f - u) * (1.0f - u));
}

__global__ __launch_bounds__(256)
void prroi_kernel(const float* __restrict__ feat,
                  const float* __restrict__ bb,
                  float* __restrict__ out) {
    __shared__ float gy_lds[GYR][4];              // rows j0.., zero past j1
    __shared__ float gx_lds[4][SPAD];
    __shared__ float s_lds[CPB * 4][SPAD];        // [(ch*4+p)][lane]

    const int bid = blockIdx.x;
    const int n   = bid >> 5;          // 8 distinct n per CU (stride-256 sampling)
    const int cg  = bid & 31;          // 0..31 channel-group
    const int tid = (int)threadIdx.x;
    const int w      = tid >> 6;
    const int lane   = tid & 63;
    const int coll   = lane & 31;      // column offset within ROI window
    const int parity = lane >> 5;      // row parity this lane handles

    const float bx = bb[n*4+0], by = bb[n*4+1], bw = bb[n*4+2], bh = bb[n*4+3];
    const float inv_s = 1.0f / 16.0f;
    const float x1 = bx*inv_s,        y1 = by*inv_s;
    const float x2 = (bx+bw)*inv_s,   y2 = (by+bh)*inv_s;
    const float binw = (x2-x1)*0.25f, binh = (y2-y1)*0.25f;

    // Support of the bilinear weights: i in (x1-1, x2+1); integer span <= 30.
    const int i0 = max((int)ceilf(x1 - 1.0f), 0);
    const int i1 = min((int)floorf(x2 + 1.0f), W_-1);
    const int j0 = max((int)ceilf(y1 - 1.0f), 0);
    const int j1 = min((int)floorf(y2 + 1.0f), H_-1);

    // ---- weight tables (once per block) ----
    if (tid < GYR * 4) {               // 32 rows x 4 bins (zeros past j1)
        const int r = tid >> 2, p = tid & 3;
        const int h = j0 + r;
        float v = 0.0f;
        if (h <= j1) {
            const float a = y1 + (float)p * binh, b = a + binh;
            v = Gfun(b - (float)h) - Gfun(a - (float)h);
        }
        gy_lds[r][p] = v;
    }
    {                                  // gx duplicated across both parities
        const int q = tid >> 6, l = tid & 63;
        const int col = i0 + (l & 31);
        float v = 0.0f;
        if (col <= i1) {
            const float a = x1 + (float)q * binw, b = a + binw;
            v = Gfun(b - (float)col) - Gfun(a - (float)col);
        }
        gx_lds[q][l] = v;
    }
    __syncthreads();

    // ---- phase 1: row-weighted column sums, one HBM round ----
    const int colc = min(i0 + coll, i1);
    const float* fb = feat + (size_t)(n*C_ + cg*CPB + w*CPW) * HW_;
    const float* fb1 = fb + HW_;

    float f[CPW][KCH];
    #pragma unroll
    for (int k = 0; k < KCH; ++k) { f[0][k] = 0.0f; f[1][k] = 0.0f; }

    // Guarded load cluster: condition is block-uniform (scalar branch), so
    // skipped chunks cost ~nothing and issued loads stay back-to-back.
    #pragma unroll
    for (int k = 0; k < KCH; ++k) {
        if (j0 + 2*k <= j1) {
            const int a = min(j0 + parity + 2*k, j1)*W_ + colc;
            f[0][k] = fb[a];
            f[1][k] = fb1[a];
        }
    }

    float s[CPW][4] = {};
    #pragma unroll
    for (int k = 0; k < KCH; ++k) {
        const float4 gy = *reinterpret_cast<const float4*>(&gy_lds[parity + 2*k][0]);
        #pragma unroll
        for (int c = 0; c < CPW; ++c) {
            s[c][0] = fmaf(gy.x, f[c][k], s[c][0]);
            s[c][1] = fmaf(gy.y, f[c][k], s[c][1]);
            s[c][2] = fmaf(gy.z, f[c][k], s[c][2]);
            s[c][3] = fmaf(gy.w, f[c][k], s[c][3]);
        }
    }

    #pragma unroll
    for (int c = 0; c < CPW; ++c)
        #pragma unroll
        for (int p = 0; p < 4; ++p)
            s_lds[(w*CPW + c)*4 + p][lane] = s[c][p];   // 64 consecutive cols: conflict-free
    __syncthreads();

    // ---- phase 2: one output per thread (tid < 128); out offset == tid ----
    if (tid < CPB * 16) {
        const int q = tid & 3;
        const int rowi = tid >> 2;               // (ch*4 + p), 0..31
        const float* srow = &s_lds[rowi][0];
        const float* gxr  = &gx_lds[q][0];
        float acc = 0.0f;
        #pragma unroll
        for (int i = 0; i < 16; ++i) {
            const float4 sv = *reinterpret_cast<const float4*>(srow + i*4);
            const float4 gv = *reinterpret_cast<const float4*>(gxr  + i*4);
            acc += sv.x*gv.x + sv.y*gv.y + sv.z*gv.z + sv.w*gv.w;
        }
        const float area = fmaxf(binw * binh, 0.0f);
        const float inv  = (area > 0.0f) ? (1.0f / fmaxf(area, 1e-12f)) : 0.0f;
        out[(size_t)(n*C_ + cg*CPB) * 16 + tid] = acc * inv;
    }
}

extern "C" void kernel_launch(void* const* d_in, const int* in_sizes, int n_in,
                              void* d_out, int out_size, void* d_ws, size_t ws_size,
                              hipStream_t stream) {
    const float* feat = (const float*)d_in[0];
    const float* bb   = (const float*)d_in[1];
    float* outp       = (float*)d_out;
    prroi_kernel<<<dim3(N_ * (C_ / CPB)), dim3(256), 0, stream>>>(feat, bb, outp);
}